// Round 10
// baseline (323.586 us; speedup 1.0000x reference)
//
#include <hip/hip_runtime.h>
#include <hip/hip_bf16.h>
#include <math.h>

#define NRAYS 4096
#define KK    12
#define GS    160
#define G3    (GS*GS*GS)
#define NSAMP (NRAYS*256)

typedef __bf16 bf16x8 __attribute__((ext_vector_type(8)));
typedef float  f32x4  __attribute__((ext_vector_type(4)));

// d_ws layout (bytes):
//  [0, 45056): weights bf16: w0kT [128][32] @0, w1T [128][128] @8192B, w2T [16][128] @40960B
//  [65536, 131137536): interleaved grid bf16 [G3][16] = {den,std,k0[0..11],0,0}
//  [131137536, 164691968): feat  uint4[NSAMP*2]  (32 B/sample)
//  [164691968, 181469184): wk_a  uint4[NSAMP]    (wk[0..7] bf16)
//  [181469184, 189857792): wk_b  uint2[NSAMP]    (wk[8..11] bf16)
#define W0KT_OFF 0
#define W1T_OFF  4096
#define W2T_OFF  20480
#define GRID_OFF_B 65536
#define FEAT_OFF_B 131137536UL
#define WKA_OFF_B  164691968UL
#define WKB_OFF_B  181469184UL
#define NEED_SPLIT 189857792UL
#define NEED_GRID  131137536UL

__device__ __forceinline__ float softplusf(float x) {
    return fmaxf(x, 0.f) + log1pf(expf(-fabsf(x)));
}
__device__ __forceinline__ float sigmoidf(float x) {
    return 1.f / (1.f + __expf(-x));
}
__device__ __forceinline__ unsigned pk2(float a, float b) {
    unsigned short x = __builtin_bit_cast(unsigned short, (__bf16)a);
    unsigned short y = __builtin_bit_cast(unsigned short, (__bf16)b);
    return (unsigned)x | ((unsigned)y << 16);
}
__device__ __forceinline__ float bfw(unsigned u, int hi) {
    return __builtin_bit_cast(float, hi ? (u & 0xffff0000u) : (u << 16));
}
// XOR swizzle for 256B-row LDS tiles (acts AND W1): kills same-bank stride-256 reads
__device__ __forceinline__ int xoff(int m, int kb) {
    return m * 256 + (kb ^ ((m & 7) << 4));
}

__global__ void prep_weights(const float* __restrict__ w0, const float* __restrict__ w1,
                             const float* __restrict__ w2, __bf16* __restrict__ ws)
{
    int i = blockIdx.x * 256 + threadIdx.x;
    if (i < 4096) {                       // w0kT [n][k<32], k<12 valid
        int n = i >> 5, k = i & 31;
        ws[W0KT_OFF + i] = (__bf16)((k < 12) ? w0[k * 128 + n] : 0.f);
    } else if (i < 20480) {               // w1T [n][k<128]
        int j = i - 4096;
        int n = j >> 7, k = j & 127;
        ws[W1T_OFF + j] = (__bf16)(w1[k * 128 + n]);
    } else if (i < 22528) {               // w2T [n<16][k<128]
        int j = i - 20480;
        int n = j >> 7, k = j & 127;
        ws[W2T_OFF + j] = (__bf16)((n < 6) ? w2[k * 6 + n] : 0.f);
    }
}

__global__ void prep_grid(const float* __restrict__ dg, const float* __restrict__ sg,
                          const float* __restrict__ k0, __bf16* __restrict__ dst)
{
    int v = blockIdx.x * 256 + threadIdx.x;
    float vals[16];
    vals[0] = dg[v];
    vals[1] = sg[v];
#pragma unroll
    for (int c = 0; c < 12; ++c) vals[2 + c] = k0[c * G3 + v];
    vals[14] = 0.f; vals[15] = 0.f;
    uint4 o0, o1;
    o0.x = pk2(vals[0],  vals[1]);  o0.y = pk2(vals[2],  vals[3]);
    o0.z = pk2(vals[4],  vals[5]);  o0.w = pk2(vals[6],  vals[7]);
    o1.x = pk2(vals[8],  vals[9]);  o1.y = pk2(vals[10], vals[11]);
    o1.z = pk2(vals[12], vals[13]); o1.w = pk2(vals[14], vals[15]);
    uint4* p = (uint4*)(dst + (size_t)v * 16);
    p[0] = o0; p[1] = o1;
}

// ========================= Kernel A: gather + scan =========================
__global__ __launch_bounds__(256, 2)
void voxgo_gather(const float* __restrict__ rays_o, const float* __restrict__ rays_d,
                  const char* __restrict__ gridb, const float* __restrict__ eps_den,
                  uint4* __restrict__ feat, uint4* __restrict__ wk_a,
                  uint2* __restrict__ wk_b, float* __restrict__ out)
{
    const float BGL   = 0.2f;
    const float XMIN  = -1.2f;
    const float SCALE = 159.0f / 2.4f;
    const float ACT_SHIFT = -9.2102403672f;
    const float STEP  = 0.0075f;
    const float NEART = 0.1f;

    __shared__ float scanw[4][KK];

    const int r    = blockIdx.x;
    const int s    = threadIdx.x;
    const int lane = s & 63;
    const int wv   = s >> 6;

    if (s < 3) out[r*3 + s] = 1.0f;       // init for kernel B's atomics

    float dx = rays_d[r*3+0], dy = rays_d[r*3+1], dz = rays_d[r*3+2];
    float inv = rsqrtf(dx*dx + dy*dy + dz*dz);
    dx *= inv; dy *= inv; dz *= inv;
    float t  = NEART + STEP * (float)s;
    float px = rays_o[r*3+0] + dx*t;
    float py = rays_o[r*3+1] + dy*t;
    float pz = rays_o[r*3+2] + dz*t;
    float an = fmaxf(fabsf(px), fmaxf(fabsf(py), fabsf(pz)));
    if (an > 1.0f) {
        float sc = (1.0f + BGL - BGL/an) / an;
        px *= sc; py *= sc; pz *= sc;
    }
    float ux = (px - XMIN)*SCALE, uy = (py - XMIN)*SCALE, uz = (pz - XMIN)*SCALE;
    int ix = min(max((int)floorf(ux), 0), GS-2);
    int iy = min(max((int)floorf(uy), 0), GS-2);
    int iz = min(max((int)floorf(uz), 0), GS-2);
    float fx = ux-(float)ix, fy = uy-(float)iy, fz = uz-(float)iz;
    float gx = 1.f-fx, gy = 1.f-fy, gz = 1.f-fz;
    const int o000 = (ix*GS + iy)*GS + iz;
    float c00 = gx*gy, c01 = gx*fy, c10 = fx*gy, c11 = fx*fy;

    float acc14[14];
#pragma unroll
    for (int c = 0; c < 14; ++c) acc14[c] = 0.f;
    const int   vi[4] = { o000, o000 + GS, o000 + GS*GS, o000 + GS*GS + GS };
    const float cw[4] = { c00, c01, c10, c11 };
#pragma unroll
    for (int p = 0; p < 4; ++p) {
        const uint4* vp = (const uint4*)(gridb + (size_t)vi[p] * 32);
        uint4 q0 = vp[0], q1 = vp[1], q2 = vp[2], q3 = vp[3];
        float wz0 = cw[p]*gz, wz1 = cw[p]*fz;
        unsigned z0w[8] = { q0.x, q0.y, q0.z, q0.w, q1.x, q1.y, q1.z, q1.w };
        unsigned z1w[8] = { q2.x, q2.y, q2.z, q2.w, q3.x, q3.y, q3.z, q3.w };
#pragma unroll
        for (int c = 0; c < 14; ++c) {
            float a = bfw(z0w[c >> 1], c & 1);
            float b = bfw(z1w[c >> 1], c & 1);
            acc14[c] = fmaf(wz0, a, fmaf(wz1, b, acc14[c]));
        }
    }
    float raw_den = acc14[0];
    float raw_std = acc14[1];

    float stdv = softplusf(raw_std);
    float alpha[KK], incl[KK];
#pragma unroll
    for (int k = 0; k < KK; ++k) {
        float x  = raw_den + stdv * eps_den[k] + ACT_SHIFT;
        float a  = __expf(x) * 0.5f;
        float al = a - a*a*0.5f;
        alpha[k] = al;
        incl[k]  = 1.f - al + 1e-10f;
    }
#pragma unroll
    for (int d = 1; d < 64; d <<= 1) {
#pragma unroll
        for (int k = 0; k < KK; ++k) {
            float v = __shfl_up(incl[k], d, 64);
            if (lane >= d) incl[k] *= v;
        }
    }
    if (lane == 63) {
#pragma unroll
        for (int k = 0; k < KK; ++k) scanw[wv][k] = incl[k];
    }
    __syncthreads();
    float wk[KK];
#pragma unroll
    for (int k = 0; k < KK; ++k) {
        float pref = 1.f;
        for (int pw = 0; pw < wv; ++pw) pref *= scanw[pw][k];
        float ex = __shfl_up(incl[k], 1, 64);
        if (lane == 0) ex = 1.f;
        wk[k] = alpha[k] * (pref * ex);
    }

    const int rid = r * 256 + s;
    uint4 q0, q1;
    q0.x = pk2(acc14[2], acc14[3]);  q0.y = pk2(acc14[4],  acc14[5]);
    q0.z = pk2(acc14[6], acc14[7]);  q0.w = pk2(acc14[8],  acc14[9]);
    q1.x = pk2(acc14[10], acc14[11]); q1.y = pk2(acc14[12], acc14[13]);
    q1.z = 0u; q1.w = 0u;
    feat[(size_t)rid*2 + 0] = q0;
    feat[(size_t)rid*2 + 1] = q1;
    uint4 wa; uint2 wb;
    wa.x = pk2(wk[0], wk[1]); wa.y = pk2(wk[2], wk[3]);
    wa.z = pk2(wk[4], wk[5]); wa.w = pk2(wk[6], wk[7]);
    wb.x = pk2(wk[8], wk[9]); wb.y = pk2(wk[10], wk[11]);
    wk_a[rid] = wa;
    wk_b[rid] = wb;
}

// ========================= Kernel B: LDS-fed GEMM MLP ======================
// 256 threads (4 waves), (256,2) -> arch VGPR 128 (only proven healthy regime).
// Block = 64 samples (quarter-ray). ALL weights staged in LDS; W1 swizzled.
// Straight-line MLP, acc[8] = 32 VGPRs, wave owns 16 rows.
__global__ __launch_bounds__(256, 2)
void voxgo_mlp(const float* __restrict__ rays_d,
               const float* __restrict__ w0, const float* __restrict__ b0,
               const float* __restrict__ b1, const float* __restrict__ b2,
               const float* __restrict__ eps_rgb,
               const __bf16* __restrict__ wsb,
               const uint4* __restrict__ feat, const uint4* __restrict__ wk_a,
               const uint2* __restrict__ wk_b,
               float* __restrict__ out)
{
    __shared__ char   wl[32768];       // W1T [128][128] bf16, xoff-swizzled rows
    __shared__ __bf16 w0l[128*32];     // 8 KB linear
    __shared__ __bf16 w2l[16*128];     // 4 KB linear
    __shared__ char   act[64*256];     // 16 KB act rows (xoff), 16 rows per wave
    __shared__ float  h1ray[128];
    __shared__ float  veb[32];
    __shared__ float  red[4][4];

    const int blk  = blockIdx.x;
    const int r    = blk >> 2;         // ray
    const int q    = blk & 3;          // quarter (64 samples)
    const int s    = threadIdx.x;
    const int lane = s & 63;
    const int wv   = s >> 6;
    const int lm = lane & 15, lk = lane >> 4;
    const int Mb = wv * 16;            // wave's 16-row slice

    // ---- stage weights into LDS (once per block) ----
    {
        const uint4* g1 = (const uint4*)(wsb + W1T_OFF);   // 2048 uint4
#pragma unroll
        for (int j = 0; j < 8; ++j) {
            int i = j * 256 + s;
            *(uint4*)(wl + xoff(i >> 4, (i & 15) << 4)) = g1[i];
        }
        const uint4* g0 = (const uint4*)(wsb + W0KT_OFF);  // 512 uint4
        ((uint4*)w0l)[s]       = g0[s];
        ((uint4*)w0l)[s + 256] = g0[s + 256];
        const uint4* g2 = (const uint4*)(wsb + W2T_OFF);   // 256 uint4
        ((uint4*)w2l)[s] = g2[s];
    }

    // ---- viewdir embedding ----
    float dx = rays_d[r*3+0], dy = rays_d[r*3+1], dz = rays_d[r*3+2];
    float inv = rsqrtf(dx*dx + dy*dy + dz*dz);
    dx *= inv; dy *= inv; dz *= inv;
    if (s < 27) {
        float v;
        if (s < 3)       v = (s == 0) ? dx : (s == 1) ? dy : dz;
        else {
            int j = (s - 3) % 12;
            int a = j >> 2, p = j & 3;
            float arg = ((a == 0) ? dx : (a == 1) ? dy : dz) * (float)(1 << p);
            float sv, cv;
            __sincosf(arg, &sv, &cv);
            v = (s < 15) ? sv : cv;
        }
        veb[s] = v;
    }

    // ---- act tile fill: thread s -> row s>>2, part s&3 ----
    {
        const int row  = s >> 2;
        const int part = s & 3;
        const size_t rid = (size_t)r * 256 + q * 64 + row;
        uint4 v = {0u, 0u, 0u, 0u};
        if (part < 2) v = feat[rid * 2 + part];
        *(uint4*)(act + xoff(row, part * 16)) = v;
    }
    __syncthreads();   // [1] veb + weights + act visible

    // ---- h1ray[n] = b0[n] + W0[12:39]^T . ve ----
    if (s < 128) {
        float acc = b0[s];
#pragma unroll
        for (int j = 0; j < 27; ++j)
            acc = fmaf(veb[j], w0[(12 + j) * 128 + s], acc);
        h1ray[s] = acc;
    }
    __syncthreads();   // [2] h1ray visible

    // ================= MLP (straight-line, weights from LDS) ==============
    f32x4 acc[8];
    // ---- L1: K=32 (12 real)
#pragma unroll
    for (int nt = 0; nt < 8; ++nt)
        acc[nt] = *(const f32x4*)(h1ray + nt*16 + lk*4);
    {
        bf16x8 bfr = *(const bf16x8*)(act + xoff(Mb + lm, lk*16));
#pragma unroll
        for (int nt = 0; nt < 8; ++nt) {
            bf16x8 af = *(const bf16x8*)(w0l + (nt*16 + lm)*32 + lk*8);
            acc[nt] = __builtin_amdgcn_mfma_f32_16x16x32_bf16(af, bfr, acc[nt], 0, 0, 0);
        }
    }
    // relu -> h1 (own rows)
#pragma unroll
    for (int nt = 0; nt < 8; ++nt) {
        f32x4 v = acc[nt];
        uint2 p;
        p.x = pk2(fmaxf(v.x, 0.f), fmaxf(v.y, 0.f));
        p.y = pk2(fmaxf(v.z, 0.f), fmaxf(v.w, 0.f));
        *(uint2*)(act + xoff(Mb + lm, nt*32 + lk*8)) = p;
    }
    // ---- L2: 128 -> 128, weights from swizzled LDS
#pragma unroll
    for (int nt = 0; nt < 8; ++nt) {
        int n0 = nt*16 + lk*4;
        f32x4 bi = { b1[n0], b1[n0+1], b1[n0+2], b1[n0+3] };
        acc[nt] = bi;
    }
#pragma unroll
    for (int ks = 0; ks < 4; ++ks) {
        bf16x8 bfr = *(const bf16x8*)(act + xoff(Mb + lm, ks*64 + lk*16));
#pragma unroll
        for (int nt = 0; nt < 8; ++nt) {
            bf16x8 af = *(const bf16x8*)(wl + xoff(nt*16 + lm, ks*64 + lk*16));
            acc[nt] = __builtin_amdgcn_mfma_f32_16x16x32_bf16(af, bfr, acc[nt], 0, 0, 0);
        }
    }
    // relu -> h2 (own rows)
#pragma unroll
    for (int nt = 0; nt < 8; ++nt) {
        f32x4 v = acc[nt];
        uint2 p;
        p.x = pk2(fmaxf(v.x, 0.f), fmaxf(v.y, 0.f));
        p.y = pk2(fmaxf(v.z, 0.f), fmaxf(v.w, 0.f));
        *(uint2*)(act + xoff(Mb + lm, nt*32 + lk*8)) = p;
    }
    // ---- L3: 128 -> 16 (cols 0..5 valid)
    f32x4 a3;
    a3.x = (lk*4+0 < 6) ? b2[lk*4+0] : 0.f;
    a3.y = (lk*4+1 < 6) ? b2[lk*4+1] : 0.f;
    a3.z = (lk*4+2 < 6) ? b2[lk*4+2] : 0.f;
    a3.w = (lk*4+3 < 6) ? b2[lk*4+3] : 0.f;
#pragma unroll
    for (int ks = 0; ks < 4; ++ks) {
        bf16x8 af  = *(const bf16x8*)(w2l + lm*128 + ks*32 + lk*8);
        bf16x8 bfr = *(const bf16x8*)(act + xoff(Mb + lm, ks*64 + lk*16));
        a3 = __builtin_amdgcn_mfma_f32_16x16x32_bf16(af, bfr, a3, 0, 0, 0);
    }
    // o6 overlay into wave's own 4 KB slab (in-wave ordering; rows 16 x 80B)
    *(f32x4*)(act + wv*4096 + lm*80 + lk*16) = a3;
    __syncthreads();   // [3] all o6 visible

    // ================= rgb march: thread -> row s&63, k-part s>>6 (3 k's) ==
    float p0 = 0.f, p1 = 0.f, p2 = 0.f;
    {
        const int row  = s & 63;
        const int part = s >> 6;
        const float* orow = (const float*)(act + (row >> 4)*4096 + (row & 15)*80);
        float m0 = orow[0], m1 = orow[1], m2 = orow[2];
        float s0 = softplusf(orow[3]), s1 = softplusf(orow[4]), s2 = softplusf(orow[5]);
        const size_t rid = (size_t)r * 256 + q * 64 + row;
        uint4 wa = wk_a[rid];
        uint2 wb = wk_b[rid];
        // k = 3*part + {0,1,2}; select via ternary chains (no dynamic reg indexing)
        float wv0 = (part==0) ? bfw(wa.x,0) : (part==1) ? bfw(wa.y,1)
                  : (part==2) ? bfw(wa.w,0) : bfw(wb.x,1);
        float wv1 = (part==0) ? bfw(wa.x,1) : (part==1) ? bfw(wa.z,0)
                  : (part==2) ? bfw(wa.w,1) : bfw(wb.y,0);
        float wv2 = (part==0) ? bfw(wa.y,0) : (part==1) ? bfw(wa.z,1)
                  : (part==2) ? bfw(wb.x,0) : bfw(wb.y,1);
        float w3[3] = { wv0, wv1, wv2 };
        const int kb = part * 3;
#pragma unroll
        for (int kk = 0; kk < 3; ++kk) {
            int k = kb + kk;
            float w = w3[kk];
            p0 += w * (sigmoidf(m0 + s0*eps_rgb[k*3+0]) - 1.f);
            p1 += w * (sigmoidf(m1 + s1*eps_rgb[k*3+1]) - 1.f);
            p2 += w * (sigmoidf(m2 + s2*eps_rgb[k*3+2]) - 1.f);
        }
    }
#pragma unroll
    for (int d = 32; d > 0; d >>= 1) {
        p0 += __shfl_down(p0, d, 64);
        p1 += __shfl_down(p1, d, 64);
        p2 += __shfl_down(p2, d, 64);
    }
    if (lane == 0) { red[wv][0] = p0; red[wv][1] = p1; red[wv][2] = p2; }
    __syncthreads();   // [4]
    if (s == 0) {
        float a0 = red[0][0] + red[1][0] + red[2][0] + red[3][0];
        float a1 = red[0][1] + red[1][1] + red[2][1] + red[3][1];
        float a2 = red[0][2] + red[1][2] + red[2][2] + red[3][2];
        atomicAdd(&out[r*3+0], a0 * (1.f/12.f));
        atomicAdd(&out[r*3+1], a1 * (1.f/12.f));
        atomicAdd(&out[r*3+2], a2 * (1.f/12.f));
    }
}

// ================= fallback monolith (round-6 proven) ======================
template<int ITL>
__global__ __launch_bounds__(256, 2)
void voxgo_fwd(const float* __restrict__ rays_o, const float* __restrict__ rays_d,
               const float* __restrict__ dgrid, const float* __restrict__ sgrid,
               const float* __restrict__ k0g, const char* __restrict__ gridb,
               const float* __restrict__ w0, const float* __restrict__ b0,
               const float* __restrict__ b1, const float* __restrict__ b2,
               const float* __restrict__ eps_den, const float* __restrict__ eps_rgb,
               const __bf16* __restrict__ wsb,
               float* __restrict__ out)
{
    const float BGL   = 0.2f;
    const float XMIN  = -1.2f;
    const float SCALE = 159.0f / 2.4f;
    const float ACT_SHIFT = -9.2102403672f;
    const float STEP  = 0.0075f;
    const float NEART = 0.1f;

    __shared__ char  xb[65536];
    __shared__ float h1ray[128];
    __shared__ float veb[27];
    __shared__ float scanw[4][KK];
    __shared__ float red[4][3];

    const int r    = blockIdx.x;
    const int s    = threadIdx.x;
    const int lane = s & 63;
    const int wv   = s >> 6;
    const int lm = lane & 15, lk = lane >> 4;
    const int Mb = wv * 64;

    float dx = rays_d[r*3+0], dy = rays_d[r*3+1], dz = rays_d[r*3+2];
    float inv = rsqrtf(dx*dx + dy*dy + dz*dz);
    dx *= inv; dy *= inv; dz *= inv;
    if (s < 27) {
        float v;
        if (s < 3)       v = (s == 0) ? dx : (s == 1) ? dy : dz;
        else {
            int j = (s - 3) % 12;
            int a = j >> 2, p = j & 3;
            float arg = ((a == 0) ? dx : (a == 1) ? dy : dz) * (float)(1 << p);
            float sv, cv;
            __sincosf(arg, &sv, &cv);
            v = (s < 15) ? sv : cv;
        }
        veb[s] = v;
    }
    float t  = NEART + STEP * (float)s;
    float px = rays_o[r*3+0] + dx*t;
    float py = rays_o[r*3+1] + dy*t;
    float pz = rays_o[r*3+2] + dz*t;
    float an = fmaxf(fabsf(px), fmaxf(fabsf(py), fabsf(pz)));
    if (an > 1.0f) {
        float sc = (1.0f + BGL - BGL/an) / an;
        px *= sc; py *= sc; pz *= sc;
    }
    float ux = (px - XMIN)*SCALE, uy = (py - XMIN)*SCALE, uz = (pz - XMIN)*SCALE;
    int ix = min(max((int)floorf(ux), 0), GS-2);
    int iy = min(max((int)floorf(uy), 0), GS-2);
    int iz = min(max((int)floorf(uz), 0), GS-2);
    float fx = ux-(float)ix, fy = uy-(float)iy, fz = uz-(float)iz;
    float gx = 1.f-fx, gy = 1.f-fy, gz = 1.f-fz;
    const int o000 = (ix*GS + iy)*GS + iz;
    float c00 = gx*gy, c01 = gx*fy, c10 = fx*gy, c11 = fx*fy;

    float raw_den, raw_std, k0v[KK];
    if constexpr (ITL) {
        float acc14[14];
#pragma unroll
        for (int c = 0; c < 14; ++c) acc14[c] = 0.f;
        const int   vi[4] = { o000, o000 + GS, o000 + GS*GS, o000 + GS*GS + GS };
        const float cw[4] = { c00, c01, c10, c11 };
#pragma unroll
        for (int p = 0; p < 4; ++p) {
            const uint4* vp = (const uint4*)(gridb + (size_t)vi[p] * 32);
            uint4 q0 = vp[0], q1 = vp[1], q2 = vp[2], q3 = vp[3];
            float wz0 = cw[p]*gz, wz1 = cw[p]*fz;
            unsigned z0w[8] = { q0.x, q0.y, q0.z, q0.w, q1.x, q1.y, q1.z, q1.w };
            unsigned z1w[8] = { q2.x, q2.y, q2.z, q2.w, q3.x, q3.y, q3.z, q3.w };
#pragma unroll
            for (int c = 0; c < 14; ++c) {
                float a = bfw(z0w[c >> 1], c & 1);
                float b = bfw(z1w[c >> 1], c & 1);
                acc14[c] = fmaf(wz0, a, fmaf(wz1, b, acc14[c]));
            }
        }
        raw_den = acc14[0];
        raw_std = acc14[1];
#pragma unroll
        for (int c = 0; c < KK; ++c) k0v[c] = acc14[2 + c];
    } else {
        const int oY = GS, oX = GS*GS;
        auto tri = [&](const float* __restrict__ g) -> float {
            float v00 = g[o000]*gz       + g[o000+1]*fz;
            float v01 = g[o000+oY]*gz    + g[o000+oY+1]*fz;
            float v10 = g[o000+oX]*gz    + g[o000+oX+1]*fz;
            float v11 = g[o000+oX+oY]*gz + g[o000+oX+oY+1]*fz;
            return v00*c00 + v01*c01 + v10*c10 + v11*c11;
        };
        raw_den = tri(dgrid);
        raw_std = tri(sgrid);
#pragma unroll
        for (int c = 0; c < KK; ++c) k0v[c] = tri(k0g + c*G3);
    }

    float stdv = softplusf(raw_std);
    float alpha[KK], incl[KK];
#pragma unroll
    for (int k = 0; k < KK; ++k) {
        float x  = raw_den + stdv * eps_den[k] + ACT_SHIFT;
        float a  = __expf(x) * 0.5f;
        float al = a - a*a*0.5f;
        alpha[k] = al;
        incl[k]  = 1.f - al + 1e-10f;
    }
#pragma unroll
    for (int d = 1; d < 64; d <<= 1) {
#pragma unroll
        for (int k = 0; k < KK; ++k) {
            float v = __shfl_up(incl[k], d, 64);
            if (lane >= d) incl[k] *= v;
        }
    }
    if (lane == 63) {
#pragma unroll
        for (int k = 0; k < KK; ++k) scanw[wv][k] = incl[k];
    }
    {
        uint4 v;
        v.x = pk2(k0v[0], k0v[1]); v.y = pk2(k0v[2],  k0v[3]);
        v.z = pk2(k0v[4], k0v[5]); v.w = pk2(k0v[6],  k0v[7]);
        *(uint4*)(xb + xoff(s, 0)) = v;
        v.x = pk2(k0v[8], k0v[9]); v.y = pk2(k0v[10], k0v[11]);
        v.z = 0u; v.w = 0u;
        *(uint4*)(xb + xoff(s, 16)) = v;
        uint4 z4 = {0u, 0u, 0u, 0u};
        *(uint4*)(xb + xoff(s, 32)) = z4;
        *(uint4*)(xb + xoff(s, 48)) = z4;
    }
    __syncthreads();
    float wk[KK];
#pragma unroll
    for (int k = 0; k < KK; ++k) {
        float pref = 1.f;
        for (int pw = 0; pw < wv; ++pw) pref *= scanw[pw][k];
        float ex = __shfl_up(incl[k], 1, 64);
        if (lane == 0) ex = 1.f;
        wk[k] = alpha[k] * (pref * ex);
    }
    if (s < 128) {
        float acc = b0[s];
#pragma unroll
        for (int j = 0; j < 27; ++j)
            acc = fmaf(veb[j], w0[(12 + j) * 128 + s], acc);
        h1ray[s] = acc;
    }
    __syncthreads();

    f32x4 acc[4][8];
#pragma unroll
    for (int nt = 0; nt < 8; ++nt) {
        f32x4 bi = *(const f32x4*)(h1ray + nt*16 + lk*4);
#pragma unroll
        for (int mt = 0; mt < 4; ++mt) acc[mt][nt] = bi;
    }
    {
        const __bf16* w0t = wsb + W0KT_OFF;
        bf16x8 bfr[4];
#pragma unroll
        for (int mt = 0; mt < 4; ++mt)
            bfr[mt] = *(const bf16x8*)(xb + xoff(Mb + mt*16 + lm, lk*16));
#pragma unroll
        for (int nt = 0; nt < 8; ++nt) {
            bf16x8 af = *(const bf16x8*)(w0t + (nt*16 + lm)*32 + lk*8);
#pragma unroll
            for (int mt = 0; mt < 4; ++mt)
                acc[mt][nt] = __builtin_amdgcn_mfma_f32_16x16x32_bf16(af, bfr[mt], acc[mt][nt], 0, 0, 0);
        }
    }
#pragma unroll
    for (int mt = 0; mt < 4; ++mt) {
        int mr = Mb + mt*16 + lm;
#pragma unroll
        for (int nt = 0; nt < 8; ++nt) {
            f32x4 v = acc[mt][nt];
            uint2 p;
            p.x = pk2(fmaxf(v.x, 0.f), fmaxf(v.y, 0.f));
            p.y = pk2(fmaxf(v.z, 0.f), fmaxf(v.w, 0.f));
            *(uint2*)(xb + xoff(mr, nt*32 + lk*8)) = p;
        }
    }
#pragma unroll
    for (int nt = 0; nt < 8; ++nt) {
        int n0 = nt*16 + lk*4;
        f32x4 bi = { b1[n0], b1[n0+1], b1[n0+2], b1[n0+3] };
#pragma unroll
        for (int mt = 0; mt < 4; ++mt) acc[mt][nt] = bi;
    }
    {
        const __bf16* w1t = wsb + W1T_OFF;
#pragma unroll
        for (int ks = 0; ks < 4; ++ks) {
            bf16x8 bfr[4];
#pragma unroll
            for (int mt = 0; mt < 4; ++mt)
                bfr[mt] = *(const bf16x8*)(xb + xoff(Mb + mt*16 + lm, ks*64 + lk*16));
#pragma unroll
            for (int nt = 0; nt < 8; ++nt) {
                bf16x8 af = *(const bf16x8*)(w1t + (nt*16 + lm)*128 + ks*32 + lk*8);
#pragma unroll
                for (int mt = 0; mt < 4; ++mt)
                    acc[mt][nt] = __builtin_amdgcn_mfma_f32_16x16x32_bf16(af, bfr[mt], acc[mt][nt], 0, 0, 0);
            }
        }
    }
#pragma unroll
    for (int mt = 0; mt < 4; ++mt) {
        int mr = Mb + mt*16 + lm;
#pragma unroll
        for (int nt = 0; nt < 8; ++nt) {
            f32x4 v = acc[mt][nt];
            uint2 p;
            p.x = pk2(fmaxf(v.x, 0.f), fmaxf(v.y, 0.f));
            p.y = pk2(fmaxf(v.z, 0.f), fmaxf(v.w, 0.f));
            *(uint2*)(xb + xoff(mr, nt*32 + lk*8)) = p;
        }
    }
    f32x4 a3[4];
    {
        const __bf16* w2t = wsb + W2T_OFF;
        f32x4 bi;
        bi.x = (lk*4+0 < 6) ? b2[lk*4+0] : 0.f;
        bi.y = (lk*4+1 < 6) ? b2[lk*4+1] : 0.f;
        bi.z = (lk*4+2 < 6) ? b2[lk*4+2] : 0.f;
        bi.w = (lk*4+3 < 6) ? b2[lk*4+3] : 0.f;
#pragma unroll
        for (int mt = 0; mt < 4; ++mt) a3[mt] = bi;
#pragma unroll
        for (int ks = 0; ks < 4; ++ks) {
            bf16x8 af = *(const bf16x8*)(w2t + lm*128 + ks*32 + lk*8);
#pragma unroll
            for (int mt = 0; mt < 4; ++mt) {
                bf16x8 bfr = *(const bf16x8*)(xb + xoff(Mb + mt*16 + lm, ks*64 + lk*16));
                a3[mt] = __builtin_amdgcn_mfma_f32_16x16x32_bf16(af, bfr, a3[mt], 0, 0, 0);
            }
        }
    }
    {
        char* o6b = xb + wv * 16384;
#pragma unroll
        for (int mt = 0; mt < 4; ++mt)
            *(f32x4*)(o6b + (mt*16 + lm)*80 + lk*16) = a3[mt];
    }
    float p0 = 0.f, p1 = 0.f, p2 = 0.f;
    {
        const float* orow = (const float*)(xb + wv*16384 + lane*80);
        float m0 = orow[0], m1 = orow[1], m2 = orow[2];
        float s0 = softplusf(orow[3]), s1 = softplusf(orow[4]), s2 = softplusf(orow[5]);
#pragma unroll
        for (int k = 0; k < KK; ++k) {
            float w = wk[k];
            p0 += w * (sigmoidf(m0 + s0*eps_rgb[k*3+0]) - 1.f);
            p1 += w * (sigmoidf(m1 + s1*eps_rgb[k*3+1]) - 1.f);
            p2 += w * (sigmoidf(m2 + s2*eps_rgb[k*3+2]) - 1.f);
        }
    }
#pragma unroll
    for (int d = 32; d > 0; d >>= 1) {
        p0 += __shfl_down(p0, d, 64);
        p1 += __shfl_down(p1, d, 64);
        p2 += __shfl_down(p2, d, 64);
    }
    if (lane == 0) { red[wv][0] = p0; red[wv][1] = p1; red[wv][2] = p2; }
    __syncthreads();
    if (s == 0) {
        float a0 = red[0][0] + red[1][0] + red[2][0] + red[3][0];
        float a1 = red[0][1] + red[1][1] + red[2][1] + red[3][1];
        float a2 = red[0][2] + red[1][2] + red[2][2] + red[3][2];
        out[r*3+0] = 1.f + a0 * (1.f/12.f);
        out[r*3+1] = 1.f + a1 * (1.f/12.f);
        out[r*3+2] = 1.f + a2 * (1.f/12.f);
    }
}

extern "C" void kernel_launch(void* const* d_in, const int* in_sizes, int n_in,
                              void* d_out, int out_size, void* d_ws, size_t ws_size,
                              hipStream_t stream) {
    const float* rays_o  = (const float*)d_in[0];
    const float* rays_d  = (const float*)d_in[1];
    const float* dgrid   = (const float*)d_in[2];
    const float* sgrid   = (const float*)d_in[3];
    const float* k0g     = (const float*)d_in[4];
    const float* w0      = (const float*)d_in[5];
    const float* b0      = (const float*)d_in[6];
    const float* w1      = (const float*)d_in[7];
    const float* b1      = (const float*)d_in[8];
    const float* w2      = (const float*)d_in[9];
    const float* b2      = (const float*)d_in[10];
    const float* eps_den = (const float*)d_in[11];
    const float* eps_rgb = (const float*)d_in[12];
    float* out = (float*)d_out;
    __bf16* wsb = (__bf16*)d_ws;
    char*   base  = (char*)d_ws;
    char*   gridb = base + GRID_OFF_B;

    prep_weights<<<88, 256, 0, stream>>>(w0, w1, w2, wsb);
    if (ws_size >= NEED_SPLIT) {
        prep_grid<<<G3/256, 256, 0, stream>>>(dgrid, sgrid, k0g, (__bf16*)gridb);
        uint4* feat = (uint4*)(base + FEAT_OFF_B);
        uint4* wk_a = (uint4*)(base + WKA_OFF_B);
        uint2* wk_b = (uint2*)(base + WKB_OFF_B);
        voxgo_gather<<<NRAYS, 256, 0, stream>>>(rays_o, rays_d, gridb, eps_den,
                                                feat, wk_a, wk_b, out);
        voxgo_mlp<<<NRAYS*4, 256, 0, stream>>>(rays_d, w0, b0, b1, b2, eps_rgb,
                                               wsb, feat, wk_a, wk_b, out);
    } else if (ws_size >= NEED_GRID) {
        prep_grid<<<G3/256, 256, 0, stream>>>(dgrid, sgrid, k0g, (__bf16*)gridb);
        voxgo_fwd<1><<<NRAYS, 256, 0, stream>>>(rays_o, rays_d, dgrid, sgrid, k0g, gridb,
                                                w0, b0, b1, b2, eps_den, eps_rgb, wsb, out);
    } else {
        voxgo_fwd<0><<<NRAYS, 256, 0, stream>>>(rays_o, rays_d, dgrid, sgrid, k0g, gridb,
                                                w0, b0, b1, b2, eps_den, eps_rgb, wsb, out);
    }
}

// Round 11
// 290.864 us; speedup vs baseline: 1.1125x; 1.1125x over previous
//
#include <hip/hip_runtime.h>
#include <hip/hip_bf16.h>
#include <math.h>

#define NRAYS 4096
#define KK    12
#define GS    160
#define G3    (GS*GS*GS)
#define NSAMP (NRAYS*256)

typedef __bf16 bf16x8 __attribute__((ext_vector_type(8)));
typedef float  f32x4  __attribute__((ext_vector_type(4)));

// d_ws layout (bytes):
//  [0, 45056): weights bf16: w0kT [128][32] @0, w1T [128][128] @8192B, w2T [16][128] @40960B
//  [65536, 131137536): interleaved grid bf16 [G3][16] = {den,std,k0[0..11],0,0}
//  [131137536, 164691968): feat  uint4[NSAMP*2]  (32 B/sample)
//  [164691968, 181469184): wk_a  uint4[NSAMP]    (wk[0..7] bf16)
//  [181469184, 189857792): wk_b  uint2[NSAMP]    (wk[8..11] bf16)
#define W0KT_OFF 0
#define W1T_OFF  4096
#define W2T_OFF  20480
#define GRID_OFF_B 65536
#define FEAT_OFF_B 131137536UL
#define WKA_OFF_B  164691968UL
#define WKB_OFF_B  181469184UL
#define NEED_SPLIT 189857792UL
#define NEED_GRID  131137536UL

__device__ __forceinline__ float softplusf(float x) {
    // fast softplus: __logf/__expf (abs err ~1e-6, fine vs 0.02 threshold)
    return fmaxf(x, 0.f) + __logf(1.f + __expf(-fabsf(x)));
}
__device__ __forceinline__ float sigmoidf(float x) {
    return 1.f / (1.f + __expf(-x));
}
__device__ __forceinline__ unsigned pk2(float a, float b) {
    unsigned short x = __builtin_bit_cast(unsigned short, (__bf16)a);
    unsigned short y = __builtin_bit_cast(unsigned short, (__bf16)b);
    return (unsigned)x | ((unsigned)y << 16);
}
__device__ __forceinline__ float bfw(unsigned u, int hi) {
    return __builtin_bit_cast(float, hi ? (u & 0xffff0000u) : (u << 16));
}
// XOR swizzle for 256B-row LDS tiles
__device__ __forceinline__ int xoff(int m, int kb) {
    return m * 256 + (kb ^ ((m & 7) << 4));
}

__global__ void prep_weights(const float* __restrict__ w0, const float* __restrict__ w1,
                             const float* __restrict__ w2, __bf16* __restrict__ ws)
{
    int i = blockIdx.x * 256 + threadIdx.x;
    if (i < 4096) {                       // w0kT [n][k<32], k<12 valid
        int n = i >> 5, k = i & 31;
        ws[W0KT_OFF + i] = (__bf16)((k < 12) ? w0[k * 128 + n] : 0.f);
    } else if (i < 20480) {               // w1T [n][k<128]
        int j = i - 4096;
        int n = j >> 7, k = j & 127;
        ws[W1T_OFF + j] = (__bf16)(w1[k * 128 + n]);
    } else if (i < 22528) {               // w2T [n<16][k<128]
        int j = i - 20480;
        int n = j >> 7, k = j & 127;
        ws[W2T_OFF + j] = (__bf16)((n < 6) ? w2[k * 6 + n] : 0.f);
    }
}

__global__ void prep_grid(const float* __restrict__ dg, const float* __restrict__ sg,
                          const float* __restrict__ k0, __bf16* __restrict__ dst)
{
    int v = blockIdx.x * 256 + threadIdx.x;
    float vals[16];
    vals[0] = dg[v];
    vals[1] = sg[v];
#pragma unroll
    for (int c = 0; c < 12; ++c) vals[2 + c] = k0[c * G3 + v];
    vals[14] = 0.f; vals[15] = 0.f;
    uint4 o0, o1;
    o0.x = pk2(vals[0],  vals[1]);  o0.y = pk2(vals[2],  vals[3]);
    o0.z = pk2(vals[4],  vals[5]);  o0.w = pk2(vals[6],  vals[7]);
    o1.x = pk2(vals[8],  vals[9]);  o1.y = pk2(vals[10], vals[11]);
    o1.z = pk2(vals[12], vals[13]); o1.w = pk2(vals[14], vals[15]);
    uint4* p = (uint4*)(dst + (size_t)v * 16);
    p[0] = o0; p[1] = o1;
}

// ========================= Kernel A: gather + scan =========================
__global__ __launch_bounds__(256, 2)
void voxgo_gather(const float* __restrict__ rays_o, const float* __restrict__ rays_d,
                  const char* __restrict__ gridb, const float* __restrict__ eps_den,
                  uint4* __restrict__ feat, uint4* __restrict__ wk_a,
                  uint2* __restrict__ wk_b, float* __restrict__ out)
{
    const float BGL   = 0.2f;
    const float XMIN  = -1.2f;
    const float SCALE = 159.0f / 2.4f;
    const float ACT_SHIFT = -9.2102403672f;
    const float STEP  = 0.0075f;
    const float NEART = 0.1f;

    __shared__ float scanw[4][KK];

    const int r    = blockIdx.x;
    const int s    = threadIdx.x;
    const int lane = s & 63;
    const int wv   = s >> 6;

    if (s < 3) out[r*3 + s] = 1.0f;       // init for kernel B's atomics

    float dx = rays_d[r*3+0], dy = rays_d[r*3+1], dz = rays_d[r*3+2];
    float inv = rsqrtf(dx*dx + dy*dy + dz*dz);
    dx *= inv; dy *= inv; dz *= inv;
    float t  = NEART + STEP * (float)s;
    float px = rays_o[r*3+0] + dx*t;
    float py = rays_o[r*3+1] + dy*t;
    float pz = rays_o[r*3+2] + dz*t;
    float an = fmaxf(fabsf(px), fmaxf(fabsf(py), fabsf(pz)));
    if (an > 1.0f) {
        float sc = (1.0f + BGL - BGL/an) / an;
        px *= sc; py *= sc; pz *= sc;
    }
    float ux = (px - XMIN)*SCALE, uy = (py - XMIN)*SCALE, uz = (pz - XMIN)*SCALE;
    int ix = min(max((int)floorf(ux), 0), GS-2);
    int iy = min(max((int)floorf(uy), 0), GS-2);
    int iz = min(max((int)floorf(uz), 0), GS-2);
    float fx = ux-(float)ix, fy = uy-(float)iy, fz = uz-(float)iz;
    float gx = 1.f-fx, gy = 1.f-fy, gz = 1.f-fz;
    const int o000 = (ix*GS + iy)*GS + iz;
    float c00 = gx*gy, c01 = gx*fy, c10 = fx*gy, c11 = fx*fy;

    float acc14[14];
#pragma unroll
    for (int c = 0; c < 14; ++c) acc14[c] = 0.f;
    const int   vi[4] = { o000, o000 + GS, o000 + GS*GS, o000 + GS*GS + GS };
    const float cw[4] = { c00, c01, c10, c11 };
#pragma unroll
    for (int p = 0; p < 4; ++p) {
        const uint4* vp = (const uint4*)(gridb + (size_t)vi[p] * 32);
        uint4 q0 = vp[0], q1 = vp[1], q2 = vp[2], q3 = vp[3];
        float wz0 = cw[p]*gz, wz1 = cw[p]*fz;
        unsigned z0w[8] = { q0.x, q0.y, q0.z, q0.w, q1.x, q1.y, q1.z, q1.w };
        unsigned z1w[8] = { q2.x, q2.y, q2.z, q2.w, q3.x, q3.y, q3.z, q3.w };
#pragma unroll
        for (int c = 0; c < 14; ++c) {
            float a = bfw(z0w[c >> 1], c & 1);
            float b = bfw(z1w[c >> 1], c & 1);
            acc14[c] = fmaf(wz0, a, fmaf(wz1, b, acc14[c]));
        }
    }
    float raw_den = acc14[0];
    float raw_std = acc14[1];

    float stdv = softplusf(raw_std);
    float alpha[KK], incl[KK];
#pragma unroll
    for (int k = 0; k < KK; ++k) {
        float x  = raw_den + stdv * eps_den[k] + ACT_SHIFT;
        float a  = __expf(x) * 0.5f;
        float al = a - a*a*0.5f;
        alpha[k] = al;
        incl[k]  = 1.f - al + 1e-10f;
    }
#pragma unroll
    for (int d = 1; d < 64; d <<= 1) {
#pragma unroll
        for (int k = 0; k < KK; ++k) {
            float v = __shfl_up(incl[k], d, 64);
            if (lane >= d) incl[k] *= v;
        }
    }
    if (lane == 63) {
#pragma unroll
        for (int k = 0; k < KK; ++k) scanw[wv][k] = incl[k];
    }
    __syncthreads();
    float wk[KK];
#pragma unroll
    for (int k = 0; k < KK; ++k) {
        float pref = 1.f;
        for (int pw = 0; pw < wv; ++pw) pref *= scanw[pw][k];
        float ex = __shfl_up(incl[k], 1, 64);
        if (lane == 0) ex = 1.f;
        wk[k] = alpha[k] * (pref * ex);
    }

    const int rid = r * 256 + s;
    uint4 q0, q1;
    q0.x = pk2(acc14[2], acc14[3]);  q0.y = pk2(acc14[4],  acc14[5]);
    q0.z = pk2(acc14[6], acc14[7]);  q0.w = pk2(acc14[8],  acc14[9]);
    q1.x = pk2(acc14[10], acc14[11]); q1.y = pk2(acc14[12], acc14[13]);
    q1.z = 0u; q1.w = 0u;
    feat[(size_t)rid*2 + 0] = q0;
    feat[(size_t)rid*2 + 1] = q1;
    uint4 wa; uint2 wb;
    wa.x = pk2(wk[0], wk[1]); wa.y = pk2(wk[2], wk[3]);
    wa.z = pk2(wk[4], wk[5]); wa.w = pk2(wk[6], wk[7]);
    wb.x = pk2(wk[8], wk[9]); wb.y = pk2(wk[10], wk[11]);
    wk_a[rid] = wa;
    wk_b[rid] = wb;
}

// ========================= Kernel B v4: MLP + rgb =========================
// 256 threads (4 waves), (256,2) -> arch VGPR 128. Half-ray (128 samples) per
// block; wave owns 32 rows (acc[2][8] = 64 regs). Weights from L2 (no staging).
// LDS = 32KB act + ~1KB -> 4 blocks/CU = 4 waves/SIMD. Straight-line MLP.
__global__ __launch_bounds__(256, 2)
void voxgo_mlp(const float* __restrict__ rays_d,
               const float* __restrict__ w0, const float* __restrict__ b0,
               const float* __restrict__ b1, const float* __restrict__ b2,
               const float* __restrict__ eps_rgb,
               const __bf16* __restrict__ wsb,
               const uint4* __restrict__ feat, const uint4* __restrict__ wk_a,
               const uint2* __restrict__ wk_b,
               float* __restrict__ out)
{
    __shared__ char  act[128 * 256];   // 32 KB, 4 wave-private 32-row slabs
    __shared__ float h1ray[128];
    __shared__ float veb[32];
    __shared__ float red[4][4];

    const int blk  = blockIdx.x;
    const int r    = blk >> 1;         // ray
    const int hlf  = blk & 1;          // which 128 samples
    const int s    = threadIdx.x;
    const int lane = s & 63;
    const int wv   = s >> 6;
    const int lm = lane & 15, lk = lane >> 4;
    const int Mb = wv * 32;            // wave's 32-row slice

    // ---- viewdir embedding ----
    float dx = rays_d[r*3+0], dy = rays_d[r*3+1], dz = rays_d[r*3+2];
    float inv = rsqrtf(dx*dx + dy*dy + dz*dz);
    dx *= inv; dy *= inv; dz *= inv;
    if (s < 27) {
        float v;
        if (s < 3)       v = (s == 0) ? dx : (s == 1) ? dy : dz;
        else {
            int j = (s - 3) % 12;
            int a = j >> 2, p = j & 3;
            float arg = ((a == 0) ? dx : (a == 1) ? dy : dz) * (float)(1 << p);
            float sv, cv;
            __sincosf(arg, &sv, &cv);
            v = (s < 15) ? sv : cv;
        }
        veb[s] = v;
    }

    // ---- act fill: thread s -> row s>>1, part s&1 (+ zero pad cols 32..63) ----
    {
        const int row  = s >> 1;
        const int part = s & 1;
        const size_t rid = (size_t)r * 256 + hlf * 128 + row;
        uint4 v = feat[rid * 2 + part];
        *(uint4*)(act + xoff(row, part * 16)) = v;
        uint4 z4 = {0u, 0u, 0u, 0u};
        *(uint4*)(act + xoff(row, 32 + part * 16)) = z4;
    }
    __syncthreads();   // [1] veb + act visible

    // ---- h1ray[n] = b0[n] + W0[12:39]^T . ve ----
    if (s < 128) {
        float acc = b0[s];
#pragma unroll
        for (int j = 0; j < 27; ++j)
            acc = fmaf(veb[j], w0[(12 + j) * 128 + s], acc);
        h1ray[s] = acc;
    }
    __syncthreads();   // [2] h1ray visible

    // ================= MFMA MLP (wave-private rows, straight-line) =========
    f32x4 acc[2][8];
    // ---- L1: K=32 (12 real)
#pragma unroll
    for (int nt = 0; nt < 8; ++nt) {
        f32x4 bi = *(const f32x4*)(h1ray + nt*16 + lk*4);
        acc[0][nt] = bi; acc[1][nt] = bi;
    }
    {
        const __bf16* w0t = wsb + W0KT_OFF;
        bf16x8 bfr[2];
#pragma unroll
        for (int mt = 0; mt < 2; ++mt)
            bfr[mt] = *(const bf16x8*)(act + xoff(Mb + mt*16 + lm, lk*16));
#pragma unroll
        for (int nt = 0; nt < 8; ++nt) {
            bf16x8 af = *(const bf16x8*)(w0t + (nt*16 + lm)*32 + lk*8);
#pragma unroll
            for (int mt = 0; mt < 2; ++mt)
                acc[mt][nt] = __builtin_amdgcn_mfma_f32_16x16x32_bf16(af, bfr[mt], acc[mt][nt], 0, 0, 0);
        }
    }
    // relu -> h1 (own rows)
#pragma unroll
    for (int mt = 0; mt < 2; ++mt) {
        int mr = Mb + mt*16 + lm;
#pragma unroll
        for (int nt = 0; nt < 8; ++nt) {
            f32x4 v = acc[mt][nt];
            uint2 p;
            p.x = pk2(fmaxf(v.x, 0.f), fmaxf(v.y, 0.f));
            p.y = pk2(fmaxf(v.z, 0.f), fmaxf(v.w, 0.f));
            *(uint2*)(act + xoff(mr, nt*32 + lk*8)) = p;
        }
    }
    // ---- L2: 128 -> 128, weights from L2
#pragma unroll
    for (int nt = 0; nt < 8; ++nt) {
        int n0 = nt*16 + lk*4;
        f32x4 bi = { b1[n0], b1[n0+1], b1[n0+2], b1[n0+3] };
        acc[0][nt] = bi; acc[1][nt] = bi;
    }
    {
        const __bf16* w1t = wsb + W1T_OFF;
#pragma unroll
        for (int ks = 0; ks < 4; ++ks) {
            bf16x8 bfr[2];
#pragma unroll
            for (int mt = 0; mt < 2; ++mt)
                bfr[mt] = *(const bf16x8*)(act + xoff(Mb + mt*16 + lm, ks*64 + lk*16));
#pragma unroll
            for (int nt = 0; nt < 8; ++nt) {
                bf16x8 af = *(const bf16x8*)(w1t + (nt*16 + lm)*128 + ks*32 + lk*8);
#pragma unroll
                for (int mt = 0; mt < 2; ++mt)
                    acc[mt][nt] = __builtin_amdgcn_mfma_f32_16x16x32_bf16(af, bfr[mt], acc[mt][nt], 0, 0, 0);
            }
        }
    }
    // relu -> h2 (own rows)
#pragma unroll
    for (int mt = 0; mt < 2; ++mt) {
        int mr = Mb + mt*16 + lm;
#pragma unroll
        for (int nt = 0; nt < 8; ++nt) {
            f32x4 v = acc[mt][nt];
            uint2 p;
            p.x = pk2(fmaxf(v.x, 0.f), fmaxf(v.y, 0.f));
            p.y = pk2(fmaxf(v.z, 0.f), fmaxf(v.w, 0.f));
            *(uint2*)(act + xoff(mr, nt*32 + lk*8)) = p;
        }
    }
    // ---- L3: 128 -> 16 (cols 0..5 valid)
    f32x4 a3[2];
    {
        const __bf16* w2t = wsb + W2T_OFF;
        f32x4 bi;
        bi.x = (lk*4+0 < 6) ? b2[lk*4+0] : 0.f;
        bi.y = (lk*4+1 < 6) ? b2[lk*4+1] : 0.f;
        bi.z = (lk*4+2 < 6) ? b2[lk*4+2] : 0.f;
        bi.w = (lk*4+3 < 6) ? b2[lk*4+3] : 0.f;
        a3[0] = bi; a3[1] = bi;
#pragma unroll
        for (int ks = 0; ks < 4; ++ks) {
            bf16x8 af = *(const bf16x8*)(w2t + lm*128 + ks*32 + lk*8);
#pragma unroll
            for (int mt = 0; mt < 2; ++mt) {
                bf16x8 bfr = *(const bf16x8*)(act + xoff(Mb + mt*16 + lm, ks*64 + lk*16));
                a3[mt] = __builtin_amdgcn_mfma_f32_16x16x32_bf16(af, bfr, a3[mt], 0, 0, 0);
            }
        }
    }
    // ---- o6 overlay into wave's own 8 KB slab (32 rows x 80 B) ----
    {
        char* o6b = act + wv * 8192;
#pragma unroll
        for (int mt = 0; mt < 2; ++mt)
            *(f32x4*)(o6b + (mt*16 + lm)*80 + lk*16) = a3[mt];
    }
    __syncthreads();   // [3] all o6 visible

    // ================= rgb: thread -> row s&127, k-half s>>7 (6 k's each) ==
    float p0 = 0.f, p1 = 0.f, p2 = 0.f;
    {
        const int row = s & 127;
        const int hf  = s >> 7;
        const float* orow = (const float*)(act + (row >> 5)*8192 + (row & 31)*80);
        float m0 = orow[0], m1 = orow[1], m2 = orow[2];
        float s0 = softplusf(orow[3]), s1 = softplusf(orow[4]), s2 = softplusf(orow[5]);
        const size_t rid = (size_t)r * 256 + hlf * 128 + row;
        uint4 wa = wk_a[rid];
        float w6[6];
        if (hf == 0) {
            w6[0] = bfw(wa.x, 0); w6[1] = bfw(wa.x, 1); w6[2] = bfw(wa.y, 0);
            w6[3] = bfw(wa.y, 1); w6[4] = bfw(wa.z, 0); w6[5] = bfw(wa.z, 1);
        } else {
            uint2 wb = wk_b[rid];
            w6[0] = bfw(wa.w, 0); w6[1] = bfw(wa.w, 1); w6[2] = bfw(wb.x, 0);
            w6[3] = bfw(wb.x, 1); w6[4] = bfw(wb.y, 0); w6[5] = bfw(wb.y, 1);
        }
        const int kb = hf * 6;
#pragma unroll
        for (int kk = 0; kk < 6; ++kk) {
            int k = kb + kk;
            float w = w6[kk];
            p0 += w * (sigmoidf(m0 + s0*eps_rgb[k*3+0]) - 1.f);
            p1 += w * (sigmoidf(m1 + s1*eps_rgb[k*3+1]) - 1.f);
            p2 += w * (sigmoidf(m2 + s2*eps_rgb[k*3+2]) - 1.f);
        }
    }
#pragma unroll
    for (int d = 32; d > 0; d >>= 1) {
        p0 += __shfl_down(p0, d, 64);
        p1 += __shfl_down(p1, d, 64);
        p2 += __shfl_down(p2, d, 64);
    }
    if (lane == 0) { red[wv][0] = p0; red[wv][1] = p1; red[wv][2] = p2; }
    __syncthreads();   // [4]
    if (s == 0) {
        float a0 = red[0][0] + red[1][0] + red[2][0] + red[3][0];
        float a1 = red[0][1] + red[1][1] + red[2][1] + red[3][1];
        float a2 = red[0][2] + red[1][2] + red[2][2] + red[3][2];
        atomicAdd(&out[r*3+0], a0 * (1.f/12.f));
        atomicAdd(&out[r*3+1], a1 * (1.f/12.f));
        atomicAdd(&out[r*3+2], a2 * (1.f/12.f));
    }
}

// ================= fallback monolith (round-6 proven) ======================
template<int ITL>
__global__ __launch_bounds__(256, 2)
void voxgo_fwd(const float* __restrict__ rays_o, const float* __restrict__ rays_d,
               const float* __restrict__ dgrid, const float* __restrict__ sgrid,
               const float* __restrict__ k0g, const char* __restrict__ gridb,
               const float* __restrict__ w0, const float* __restrict__ b0,
               const float* __restrict__ b1, const float* __restrict__ b2,
               const float* __restrict__ eps_den, const float* __restrict__ eps_rgb,
               const __bf16* __restrict__ wsb,
               float* __restrict__ out)
{
    const float BGL   = 0.2f;
    const float XMIN  = -1.2f;
    const float SCALE = 159.0f / 2.4f;
    const float ACT_SHIFT = -9.2102403672f;
    const float STEP  = 0.0075f;
    const float NEART = 0.1f;

    __shared__ char  xb[65536];
    __shared__ float h1ray[128];
    __shared__ float veb[27];
    __shared__ float scanw[4][KK];
    __shared__ float red[4][3];

    const int r    = blockIdx.x;
    const int s    = threadIdx.x;
    const int lane = s & 63;
    const int wv   = s >> 6;
    const int lm = lane & 15, lk = lane >> 4;
    const int Mb = wv * 64;

    float dx = rays_d[r*3+0], dy = rays_d[r*3+1], dz = rays_d[r*3+2];
    float inv = rsqrtf(dx*dx + dy*dy + dz*dz);
    dx *= inv; dy *= inv; dz *= inv;
    if (s < 27) {
        float v;
        if (s < 3)       v = (s == 0) ? dx : (s == 1) ? dy : dz;
        else {
            int j = (s - 3) % 12;
            int a = j >> 2, p = j & 3;
            float arg = ((a == 0) ? dx : (a == 1) ? dy : dz) * (float)(1 << p);
            float sv, cv;
            __sincosf(arg, &sv, &cv);
            v = (s < 15) ? sv : cv;
        }
        veb[s] = v;
    }
    float t  = NEART + STEP * (float)s;
    float px = rays_o[r*3+0] + dx*t;
    float py = rays_o[r*3+1] + dy*t;
    float pz = rays_o[r*3+2] + dz*t;
    float an = fmaxf(fabsf(px), fmaxf(fabsf(py), fabsf(pz)));
    if (an > 1.0f) {
        float sc = (1.0f + BGL - BGL/an) / an;
        px *= sc; py *= sc; pz *= sc;
    }
    float ux = (px - XMIN)*SCALE, uy = (py - XMIN)*SCALE, uz = (pz - XMIN)*SCALE;
    int ix = min(max((int)floorf(ux), 0), GS-2);
    int iy = min(max((int)floorf(uy), 0), GS-2);
    int iz = min(max((int)floorf(uz), 0), GS-2);
    float fx = ux-(float)ix, fy = uy-(float)iy, fz = uz-(float)iz;
    float gx = 1.f-fx, gy = 1.f-fy, gz = 1.f-fz;
    const int o000 = (ix*GS + iy)*GS + iz;
    float c00 = gx*gy, c01 = gx*fy, c10 = fx*gy, c11 = fx*fy;

    float raw_den, raw_std, k0v[KK];
    if constexpr (ITL) {
        float acc14[14];
#pragma unroll
        for (int c = 0; c < 14; ++c) acc14[c] = 0.f;
        const int   vi[4] = { o000, o000 + GS, o000 + GS*GS, o000 + GS*GS + GS };
        const float cw[4] = { c00, c01, c10, c11 };
#pragma unroll
        for (int p = 0; p < 4; ++p) {
            const uint4* vp = (const uint4*)(gridb + (size_t)vi[p] * 32);
            uint4 q0 = vp[0], q1 = vp[1], q2 = vp[2], q3 = vp[3];
            float wz0 = cw[p]*gz, wz1 = cw[p]*fz;
            unsigned z0w[8] = { q0.x, q0.y, q0.z, q0.w, q1.x, q1.y, q1.z, q1.w };
            unsigned z1w[8] = { q2.x, q2.y, q2.z, q2.w, q3.x, q3.y, q3.z, q3.w };
#pragma unroll
            for (int c = 0; c < 14; ++c) {
                float a = bfw(z0w[c >> 1], c & 1);
                float b = bfw(z1w[c >> 1], c & 1);
                acc14[c] = fmaf(wz0, a, fmaf(wz1, b, acc14[c]));
            }
        }
        raw_den = acc14[0];
        raw_std = acc14[1];
#pragma unroll
        for (int c = 0; c < KK; ++c) k0v[c] = acc14[2 + c];
    } else {
        const int oY = GS, oX = GS*GS;
        auto tri = [&](const float* __restrict__ g) -> float {
            float v00 = g[o000]*gz       + g[o000+1]*fz;
            float v01 = g[o000+oY]*gz    + g[o000+oY+1]*fz;
            float v10 = g[o000+oX]*gz    + g[o000+oX+1]*fz;
            float v11 = g[o000+oX+oY]*gz + g[o000+oX+oY+1]*fz;
            return v00*c00 + v01*c01 + v10*c10 + v11*c11;
        };
        raw_den = tri(dgrid);
        raw_std = tri(sgrid);
#pragma unroll
        for (int c = 0; c < KK; ++c) k0v[c] = tri(k0g + c*G3);
    }

    float stdv = softplusf(raw_std);
    float alpha[KK], incl[KK];
#pragma unroll
    for (int k = 0; k < KK; ++k) {
        float x  = raw_den + stdv * eps_den[k] + ACT_SHIFT;
        float a  = __expf(x) * 0.5f;
        float al = a - a*a*0.5f;
        alpha[k] = al;
        incl[k]  = 1.f - al + 1e-10f;
    }
#pragma unroll
    for (int d = 1; d < 64; d <<= 1) {
#pragma unroll
        for (int k = 0; k < KK; ++k) {
            float v = __shfl_up(incl[k], d, 64);
            if (lane >= d) incl[k] *= v;
        }
    }
    if (lane == 63) {
#pragma unroll
        for (int k = 0; k < KK; ++k) scanw[wv][k] = incl[k];
    }
    {
        uint4 v;
        v.x = pk2(k0v[0], k0v[1]); v.y = pk2(k0v[2],  k0v[3]);
        v.z = pk2(k0v[4], k0v[5]); v.w = pk2(k0v[6],  k0v[7]);
        *(uint4*)(xb + xoff(s, 0)) = v;
        v.x = pk2(k0v[8], k0v[9]); v.y = pk2(k0v[10], k0v[11]);
        v.z = 0u; v.w = 0u;
        *(uint4*)(xb + xoff(s, 16)) = v;
        uint4 z4 = {0u, 0u, 0u, 0u};
        *(uint4*)(xb + xoff(s, 32)) = z4;
        *(uint4*)(xb + xoff(s, 48)) = z4;
    }
    __syncthreads();
    float wk[KK];
#pragma unroll
    for (int k = 0; k < KK; ++k) {
        float pref = 1.f;
        for (int pw = 0; pw < wv; ++pw) pref *= scanw[pw][k];
        float ex = __shfl_up(incl[k], 1, 64);
        if (lane == 0) ex = 1.f;
        wk[k] = alpha[k] * (pref * ex);
    }
    if (s < 128) {
        float acc = b0[s];
#pragma unroll
        for (int j = 0; j < 27; ++j)
            acc = fmaf(veb[j], w0[(12 + j) * 128 + s], acc);
        h1ray[s] = acc;
    }
    __syncthreads();

    f32x4 acc[4][8];
#pragma unroll
    for (int nt = 0; nt < 8; ++nt) {
        f32x4 bi = *(const f32x4*)(h1ray + nt*16 + lk*4);
#pragma unroll
        for (int mt = 0; mt < 4; ++mt) acc[mt][nt] = bi;
    }
    {
        const __bf16* w0t = wsb + W0KT_OFF;
        bf16x8 bfr[4];
#pragma unroll
        for (int mt = 0; mt < 4; ++mt)
            bfr[mt] = *(const bf16x8*)(xb + xoff(Mb + mt*16 + lm, lk*16));
#pragma unroll
        for (int nt = 0; nt < 8; ++nt) {
            bf16x8 af = *(const bf16x8*)(w0t + (nt*16 + lm)*32 + lk*8);
#pragma unroll
            for (int mt = 0; mt < 4; ++mt)
                acc[mt][nt] = __builtin_amdgcn_mfma_f32_16x16x32_bf16(af, bfr[mt], acc[mt][nt], 0, 0, 0);
        }
    }
#pragma unroll
    for (int mt = 0; mt < 4; ++mt) {
        int mr = Mb + mt*16 + lm;
#pragma unroll
        for (int nt = 0; nt < 8; ++nt) {
            f32x4 v = acc[mt][nt];
            uint2 p;
            p.x = pk2(fmaxf(v.x, 0.f), fmaxf(v.y, 0.f));
            p.y = pk2(fmaxf(v.z, 0.f), fmaxf(v.w, 0.f));
            *(uint2*)(xb + xoff(mr, nt*32 + lk*8)) = p;
        }
    }
#pragma unroll
    for (int nt = 0; nt < 8; ++nt) {
        int n0 = nt*16 + lk*4;
        f32x4 bi = { b1[n0], b1[n0+1], b1[n0+2], b1[n0+3] };
#pragma unroll
        for (int mt = 0; mt < 4; ++mt) acc[mt][nt] = bi;
    }
    {
        const __bf16* w1t = wsb + W1T_OFF;
#pragma unroll
        for (int ks = 0; ks < 4; ++ks) {
            bf16x8 bfr[4];
#pragma unroll
            for (int mt = 0; mt < 4; ++mt)
                bfr[mt] = *(const bf16x8*)(xb + xoff(Mb + mt*16 + lm, ks*64 + lk*16));
#pragma unroll
            for (int nt = 0; nt < 8; ++nt) {
                bf16x8 af = *(const bf16x8*)(w1t + (nt*16 + lm)*128 + ks*32 + lk*8);
#pragma unroll
                for (int mt = 0; mt < 4; ++mt)
                    acc[mt][nt] = __builtin_amdgcn_mfma_f32_16x16x32_bf16(af, bfr[mt], acc[mt][nt], 0, 0, 0);
            }
        }
    }
#pragma unroll
    for (int mt = 0; mt < 4; ++mt) {
        int mr = Mb + mt*16 + lm;
#pragma unroll
        for (int nt = 0; nt < 8; ++nt) {
            f32x4 v = acc[mt][nt];
            uint2 p;
            p.x = pk2(fmaxf(v.x, 0.f), fmaxf(v.y, 0.f));
            p.y = pk2(fmaxf(v.z, 0.f), fmaxf(v.w, 0.f));
            *(uint2*)(xb + xoff(mr, nt*32 + lk*8)) = p;
        }
    }
    f32x4 a3[4];
    {
        const __bf16* w2t = wsb + W2T_OFF;
        f32x4 bi;
        bi.x = (lk*4+0 < 6) ? b2[lk*4+0] : 0.f;
        bi.y = (lk*4+1 < 6) ? b2[lk*4+1] : 0.f;
        bi.z = (lk*4+2 < 6) ? b2[lk*4+2] : 0.f;
        bi.w = (lk*4+3 < 6) ? b2[lk*4+3] : 0.f;
#pragma unroll
        for (int mt = 0; mt < 4; ++mt) a3[mt] = bi;
#pragma unroll
        for (int ks = 0; ks < 4; ++ks) {
            bf16x8 af = *(const bf16x8*)(w2t + lm*128 + ks*32 + lk*8);
#pragma unroll
            for (int mt = 0; mt < 4; ++mt) {
                bf16x8 bfr = *(const bf16x8*)(xb + xoff(Mb + mt*16 + lm, ks*64 + lk*16));
                a3[mt] = __builtin_amdgcn_mfma_f32_16x16x32_bf16(af, bfr, a3[mt], 0, 0, 0);
            }
        }
    }
    {
        char* o6b = xb + wv * 16384;
#pragma unroll
        for (int mt = 0; mt < 4; ++mt)
            *(f32x4*)(o6b + (mt*16 + lm)*80 + lk*16) = a3[mt];
    }
    float p0 = 0.f, p1 = 0.f, p2 = 0.f;
    {
        const float* orow = (const float*)(xb + wv*16384 + lane*80);
        float m0 = orow[0], m1 = orow[1], m2 = orow[2];
        float s0 = softplusf(orow[3]), s1 = softplusf(orow[4]), s2 = softplusf(orow[5]);
#pragma unroll
        for (int k = 0; k < KK; ++k) {
            float w = wk[k];
            p0 += w * (sigmoidf(m0 + s0*eps_rgb[k*3+0]) - 1.f);
            p1 += w * (sigmoidf(m1 + s1*eps_rgb[k*3+1]) - 1.f);
            p2 += w * (sigmoidf(m2 + s2*eps_rgb[k*3+2]) - 1.f);
        }
    }
#pragma unroll
    for (int d = 32; d > 0; d >>= 1) {
        p0 += __shfl_down(p0, d, 64);
        p1 += __shfl_down(p1, d, 64);
        p2 += __shfl_down(p2, d, 64);
    }
    if (lane == 0) { red[wv][0] = p0; red[wv][1] = p1; red[wv][2] = p2; }
    __syncthreads();
    if (s == 0) {
        float a0 = red[0][0] + red[1][0] + red[2][0] + red[3][0];
        float a1 = red[0][1] + red[1][1] + red[2][1] + red[3][1];
        float a2 = red[0][2] + red[1][2] + red[2][2] + red[3][2];
        out[r*3+0] = 1.f + a0 * (1.f/12.f);
        out[r*3+1] = 1.f + a1 * (1.f/12.f);
        out[r*3+2] = 1.f + a2 * (1.f/12.f);
    }
}

extern "C" void kernel_launch(void* const* d_in, const int* in_sizes, int n_in,
                              void* d_out, int out_size, void* d_ws, size_t ws_size,
                              hipStream_t stream) {
    const float* rays_o  = (const float*)d_in[0];
    const float* rays_d  = (const float*)d_in[1];
    const float* dgrid   = (const float*)d_in[2];
    const float* sgrid   = (const float*)d_in[3];
    const float* k0g     = (const float*)d_in[4];
    const float* w0      = (const float*)d_in[5];
    const float* b0      = (const float*)d_in[6];
    const float* w1      = (const float*)d_in[7];
    const float* b1      = (const float*)d_in[8];
    const float* w2      = (const float*)d_in[9];
    const float* b2      = (const float*)d_in[10];
    const float* eps_den = (const float*)d_in[11];
    const float* eps_rgb = (const float*)d_in[12];
    float* out = (float*)d_out;
    __bf16* wsb = (__bf16*)d_ws;
    char*   base  = (char*)d_ws;
    char*   gridb = base + GRID_OFF_B;

    prep_weights<<<88, 256, 0, stream>>>(w0, w1, w2, wsb);
    if (ws_size >= NEED_SPLIT) {
        prep_grid<<<G3/256, 256, 0, stream>>>(dgrid, sgrid, k0g, (__bf16*)gridb);
        uint4* feat = (uint4*)(base + FEAT_OFF_B);
        uint4* wk_a = (uint4*)(base + WKA_OFF_B);
        uint2* wk_b = (uint2*)(base + WKB_OFF_B);
        voxgo_gather<<<NRAYS, 256, 0, stream>>>(rays_o, rays_d, gridb, eps_den,
                                                feat, wk_a, wk_b, out);
        voxgo_mlp<<<NRAYS*2, 256, 0, stream>>>(rays_d, w0, b0, b1, b2, eps_rgb,
                                               wsb, feat, wk_a, wk_b, out);
    } else if (ws_size >= NEED_GRID) {
        prep_grid<<<G3/256, 256, 0, stream>>>(dgrid, sgrid, k0g, (__bf16*)gridb);
        voxgo_fwd<1><<<NRAYS, 256, 0, stream>>>(rays_o, rays_d, dgrid, sgrid, k0g, gridb,
                                                w0, b0, b1, b2, eps_den, eps_rgb, wsb, out);
    } else {
        voxgo_fwd<0><<<NRAYS, 256, 0, stream>>>(rays_o, rays_d, dgrid, sgrid, k0g, gridb,
                                                w0, b0, b1, b2, eps_den, eps_rgb, wsb, out);
    }
}

// Round 12
// 280.481 us; speedup vs baseline: 1.1537x; 1.0370x over previous
//
#include <hip/hip_runtime.h>
#include <hip/hip_bf16.h>
#include <math.h>

#define NRAYS 4096
#define KK    12
#define GS    160
#define G3    (GS*GS*GS)

typedef __bf16 bf16x8 __attribute__((ext_vector_type(8)));
typedef float  f32x4  __attribute__((ext_vector_type(4)));

// d_ws layout:
//  bf16 [0,22528): w0kT [128][32] (k<12 valid) @0, w1T [128][128] @4096, w2T [16][128] @20480
//  bytes [65536, 65536+G3*32): interleaved grid bf16 [G3][16] = {den, std, k0[0..11], 0, 0}
#define W0KT_OFF 0
#define W1T_OFF  4096
#define W2T_OFF  20480
#define GRID_OFF_B 65536
#define NEED_GRID  (65536UL + (size_t)G3 * 32)

__device__ __forceinline__ float softplusf(float x) {
    return fmaxf(x, 0.f) + __logf(1.f + __expf(-fabsf(x)));
}
__device__ __forceinline__ float sigmoidf(float x) {
    return 1.f / (1.f + __expf(-x));
}
__device__ __forceinline__ unsigned pk2(float a, float b) {
    unsigned short x = __builtin_bit_cast(unsigned short, (__bf16)a);
    unsigned short y = __builtin_bit_cast(unsigned short, (__bf16)b);
    return (unsigned)x | ((unsigned)y << 16);
}
__device__ __forceinline__ float bfw(unsigned u, int hi) {
    return __builtin_bit_cast(float, hi ? (u & 0xffff0000u) : (u << 16));
}
// XOR swizzle for 256B-row LDS tiles
__device__ __forceinline__ int xoff(int m, int kb) {
    return m * 256 + (kb ^ ((m & 7) << 4));
}

__global__ void prep_weights(const float* __restrict__ w0, const float* __restrict__ w1,
                             const float* __restrict__ w2, __bf16* __restrict__ ws)
{
    int i = blockIdx.x * 256 + threadIdx.x;
    if (i < 4096) {                       // w0kT [n][k<32], k<12 valid
        int n = i >> 5, k = i & 31;
        ws[W0KT_OFF + i] = (__bf16)((k < 12) ? w0[k * 128 + n] : 0.f);
    } else if (i < 20480) {               // w1T [n][k<128]
        int j = i - 4096;
        int n = j >> 7, k = j & 127;
        ws[W1T_OFF + j] = (__bf16)(w1[k * 128 + n]);
    } else if (i < 22528) {               // w2T [n<16][k<128]
        int j = i - 20480;
        int n = j >> 7, k = j & 127;
        ws[W2T_OFF + j] = (__bf16)((n < 6) ? w2[k * 6 + n] : 0.f);
    }
}

__global__ void prep_grid(const float* __restrict__ dg, const float* __restrict__ sg,
                          const float* __restrict__ k0, __bf16* __restrict__ dst)
{
    int v = blockIdx.x * 256 + threadIdx.x;
    float vals[16];
    vals[0] = dg[v];
    vals[1] = sg[v];
#pragma unroll
    for (int c = 0; c < 12; ++c) vals[2 + c] = k0[c * G3 + v];
    vals[14] = 0.f; vals[15] = 0.f;
    uint4 o0, o1;
    o0.x = pk2(vals[0],  vals[1]);  o0.y = pk2(vals[2],  vals[3]);
    o0.z = pk2(vals[4],  vals[5]);  o0.w = pk2(vals[6],  vals[7]);
    o1.x = pk2(vals[8],  vals[9]);  o1.y = pk2(vals[10], vals[11]);
    o1.z = pk2(vals[12], vals[13]); o1.w = pk2(vals[14], vals[15]);
    uint4* p = (uint4*)(dst + (size_t)v * 16);
    p[0] = o0; p[1] = o1;
}

// ---- one 128-row MLP chunk, STRAIGHT-LINE (template, not runtime loop:
// runtime loops around the MFMA accumulator spill — R3/R5/R8 evidence) ----
template<int CH>
__device__ __forceinline__ void mlp_chunk(
    char* __restrict__ act, const float* __restrict__ h1ray,
    const unsigned* __restrict__ wkl,
    const float* __restrict__ b1, const float* __restrict__ b2,
    const float* __restrict__ eps_rgb, const __bf16* __restrict__ wsb,
    int s, int wv, int lm, int lk,
    unsigned f0, unsigned f1, unsigned f2, unsigned f3,
    unsigned f4, unsigned f5,
    float& p0, float& p1, float& p2)
{
    const int Mb = wv * 32;                // wave's 32-row slice of 128-row tile
    __syncthreads();                       // act free (+CH0: h1ray/wkl visible)
    if ((s >> 7) == CH) {
        int m = s & 127;
        uint4 v0 = { f0, f1, f2, f3 };
        uint4 v1 = { f4, f5, 0u, 0u };
        uint4 z4 = { 0u, 0u, 0u, 0u };
        *(uint4*)(act + xoff(m, 0))  = v0;
        *(uint4*)(act + xoff(m, 16)) = v1;
        *(uint4*)(act + xoff(m, 32)) = z4;
        *(uint4*)(act + xoff(m, 48)) = z4;
    }
    __syncthreads();                       // feats visible

    f32x4 acc[2][8];
    // ---- L1: K=32 (12 real), acc init = h1ray
#pragma unroll
    for (int nt = 0; nt < 8; ++nt) {
        f32x4 bi = *(const f32x4*)(h1ray + nt*16 + lk*4);
        acc[0][nt] = bi; acc[1][nt] = bi;
    }
    {
        const __bf16* w0t = wsb + W0KT_OFF;
        bf16x8 bfr[2];
#pragma unroll
        for (int mt = 0; mt < 2; ++mt)
            bfr[mt] = *(const bf16x8*)(act + xoff(Mb + mt*16 + lm, lk*16));
#pragma unroll
        for (int nt = 0; nt < 8; ++nt) {
            bf16x8 af = *(const bf16x8*)(w0t + (nt*16 + lm)*32 + lk*8);
#pragma unroll
            for (int mt = 0; mt < 2; ++mt)
                acc[mt][nt] = __builtin_amdgcn_mfma_f32_16x16x32_bf16(af, bfr[mt], acc[mt][nt], 0, 0, 0);
        }
    }
    // relu -> h1 (wave-private rows)
#pragma unroll
    for (int mt = 0; mt < 2; ++mt) {
        int mr = Mb + mt*16 + lm;
#pragma unroll
        for (int nt = 0; nt < 8; ++nt) {
            f32x4 v = acc[mt][nt];
            uint2 p;
            p.x = pk2(fmaxf(v.x, 0.f), fmaxf(v.y, 0.f));
            p.y = pk2(fmaxf(v.z, 0.f), fmaxf(v.w, 0.f));
            *(uint2*)(act + xoff(mr, nt*32 + lk*8)) = p;
        }
    }
    // ---- L2: 128 -> 128
#pragma unroll
    for (int nt = 0; nt < 8; ++nt) {
        int n0 = nt*16 + lk*4;
        f32x4 bi = { b1[n0], b1[n0+1], b1[n0+2], b1[n0+3] };
        acc[0][nt] = bi; acc[1][nt] = bi;
    }
    {
        const __bf16* w1t = wsb + W1T_OFF;
#pragma unroll
        for (int ks = 0; ks < 4; ++ks) {
            bf16x8 bfr[2];
#pragma unroll
            for (int mt = 0; mt < 2; ++mt)
                bfr[mt] = *(const bf16x8*)(act + xoff(Mb + mt*16 + lm, ks*64 + lk*16));
#pragma unroll
            for (int nt = 0; nt < 8; ++nt) {
                bf16x8 af = *(const bf16x8*)(w1t + (nt*16 + lm)*128 + ks*32 + lk*8);
#pragma unroll
                for (int mt = 0; mt < 2; ++mt)
                    acc[mt][nt] = __builtin_amdgcn_mfma_f32_16x16x32_bf16(af, bfr[mt], acc[mt][nt], 0, 0, 0);
            }
        }
    }
    // relu -> h2
#pragma unroll
    for (int mt = 0; mt < 2; ++mt) {
        int mr = Mb + mt*16 + lm;
#pragma unroll
        for (int nt = 0; nt < 8; ++nt) {
            f32x4 v = acc[mt][nt];
            uint2 p;
            p.x = pk2(fmaxf(v.x, 0.f), fmaxf(v.y, 0.f));
            p.y = pk2(fmaxf(v.z, 0.f), fmaxf(v.w, 0.f));
            *(uint2*)(act + xoff(mr, nt*32 + lk*8)) = p;
        }
    }
    // ---- L3: 128 -> 16 (cols 0..5 valid)
    f32x4 a3[2];
    {
        const __bf16* w2t = wsb + W2T_OFF;
        f32x4 bi;
        bi.x = (lk*4+0 < 6) ? b2[lk*4+0] : 0.f;
        bi.y = (lk*4+1 < 6) ? b2[lk*4+1] : 0.f;
        bi.z = (lk*4+2 < 6) ? b2[lk*4+2] : 0.f;
        bi.w = (lk*4+3 < 6) ? b2[lk*4+3] : 0.f;
        a3[0] = bi; a3[1] = bi;
#pragma unroll
        for (int ks = 0; ks < 4; ++ks) {
            bf16x8 af = *(const bf16x8*)(w2t + lm*128 + ks*32 + lk*8);
#pragma unroll
            for (int mt = 0; mt < 2; ++mt) {
                bf16x8 bfr = *(const bf16x8*)(act + xoff(Mb + mt*16 + lm, ks*64 + lk*16));
                a3[mt] = __builtin_amdgcn_mfma_f32_16x16x32_bf16(af, bfr, a3[mt], 0, 0, 0);
            }
        }
    }
    // ---- o6 overlay into wave's own 8 KB slab (in-wave ordering, no barrier)
    {
        char* o6b = act + wv * 8192;
#pragma unroll
        for (int mt = 0; mt < 2; ++mt)
            *(f32x4*)(o6b + (mt*16 + lm)*80 + lk*16) = a3[mt];
    }
    __syncthreads();                       // all o6 visible

    // ---- rgb partials: ALL 256 threads. row = s&127, k-half = s>>7 (6 k's)
    {
        const int row = s & 127;
        const int hf  = s >> 7;
        const float* orow = (const float*)(act + (row >> 5) * 8192 + (row & 31) * 80);
        float m0 = orow[0], m1 = orow[1], m2 = orow[2];
        float s0 = softplusf(orow[3]), s1 = softplusf(orow[4]), s2 = softplusf(orow[5]);
        const unsigned* wp = wkl + (CH * 128 + row) * 6 + hf * 3;
        unsigned wd0 = wp[0], wd1 = wp[1], wd2 = wp[2];
        float w6[6] = { bfw(wd0,0), bfw(wd0,1), bfw(wd1,0),
                        bfw(wd1,1), bfw(wd2,0), bfw(wd2,1) };
        const int kb = hf * 6;
#pragma unroll
        for (int kk = 0; kk < 6; ++kk) {
            int k = kb + kk;
            float w = w6[kk];
            p0 += w * (sigmoidf(m0 + s0*eps_rgb[k*3+0]) - 1.f);
            p1 += w * (sigmoidf(m1 + s1*eps_rgb[k*3+1]) - 1.f);
            p2 += w * (sigmoidf(m2 + s2*eps_rgb[k*3+2]) - 1.f);
        }
    }
}

template<int ITL>
__global__ __launch_bounds__(256, 2)   // (256,2): only proven VGPR-128 regime
void voxgo_fwd(const float* __restrict__ rays_o, const float* __restrict__ rays_d,
               const float* __restrict__ dgrid, const float* __restrict__ sgrid,
               const float* __restrict__ k0g, const char* __restrict__ gridb,
               const float* __restrict__ w0, const float* __restrict__ b0,
               const float* __restrict__ b1, const float* __restrict__ b2,
               const float* __restrict__ eps_den, const float* __restrict__ eps_rgb,
               const __bf16* __restrict__ wsb,
               float* __restrict__ out)
{
    const float BGL   = 0.2f;
    const float XMIN  = -1.2f;
    const float SCALE = 159.0f / 2.4f;
    const float ACT_SHIFT = -9.2102403672f;
    const float STEP  = 0.0075f;
    const float NEART = 0.1f;

    // LDS total = 32768 + 6144 + 512 + 128 + 192 + 64 = 39808 B -> 4 blocks/CU
    __shared__ char     act[128 * 256];
    __shared__ unsigned wkl[256 * 6];
    __shared__ float    h1ray[128];
    __shared__ float    veb[32];
    __shared__ float    scanw[4][KK];
    __shared__ float    red[4][4];

    const int r    = blockIdx.x;
    const int s    = threadIdx.x;
    const int lane = s & 63;
    const int wv   = s >> 6;
    const int lm = lane & 15, lk = lane >> 4;

    // ---- ray setup + viewdir embedding ----
    float dx = rays_d[r*3+0], dy = rays_d[r*3+1], dz = rays_d[r*3+2];
    float inv = rsqrtf(dx*dx + dy*dy + dz*dz);
    dx *= inv; dy *= inv; dz *= inv;
    if (s < 27) {
        float v;
        if (s < 3)       v = (s == 0) ? dx : (s == 1) ? dy : dz;
        else {
            int j = (s - 3) % 12;
            int a = j >> 2, p = j & 3;
            float arg = ((a == 0) ? dx : (a == 1) ? dy : dz) * (float)(1 << p);
            float sv, cv;
            __sincosf(arg, &sv, &cv);
            v = (s < 15) ? sv : cv;
        }
        veb[s] = v;
    }

    // ---- sample point + contraction ----
    float t  = NEART + STEP * (float)s;
    float px = rays_o[r*3+0] + dx*t;
    float py = rays_o[r*3+1] + dy*t;
    float pz = rays_o[r*3+2] + dz*t;
    float an = fmaxf(fabsf(px), fmaxf(fabsf(py), fabsf(pz)));
    if (an > 1.0f) {
        float sc = (1.0f + BGL - BGL/an) / an;
        px *= sc; py *= sc; pz *= sc;
    }
    float ux = (px - XMIN)*SCALE, uy = (py - XMIN)*SCALE, uz = (pz - XMIN)*SCALE;
    int ix = min(max((int)floorf(ux), 0), GS-2);
    int iy = min(max((int)floorf(uy), 0), GS-2);
    int iz = min(max((int)floorf(uz), 0), GS-2);
    float fx = ux-(float)ix, fy = uy-(float)iy, fz = uz-(float)iz;
    float gx = 1.f-fx, gy = 1.f-fy, gz = 1.f-fz;
    const int o000 = (ix*GS + iy)*GS + iz;
    float c00 = gx*gy, c01 = gx*fy, c10 = fx*gy, c11 = fx*fy;

    float raw_den, raw_std, k0v[KK];
    if constexpr (ITL) {
        float acc14[14];
#pragma unroll
        for (int c = 0; c < 14; ++c) acc14[c] = 0.f;
        const int   vi[4] = { o000, o000 + GS, o000 + GS*GS, o000 + GS*GS + GS };
        const float cw[4] = { c00, c01, c10, c11 };
#pragma unroll
        for (int p = 0; p < 4; ++p) {
            const uint4* vp = (const uint4*)(gridb + (size_t)vi[p] * 32);
            uint4 q0 = vp[0], q1 = vp[1], q2 = vp[2], q3 = vp[3];
            float wz0 = cw[p]*gz, wz1 = cw[p]*fz;
            unsigned z0w[8] = { q0.x, q0.y, q0.z, q0.w, q1.x, q1.y, q1.z, q1.w };
            unsigned z1w[8] = { q2.x, q2.y, q2.z, q2.w, q3.x, q3.y, q3.z, q3.w };
#pragma unroll
            for (int c = 0; c < 14; ++c) {
                float a = bfw(z0w[c >> 1], c & 1);
                float b = bfw(z1w[c >> 1], c & 1);
                acc14[c] = fmaf(wz0, a, fmaf(wz1, b, acc14[c]));
            }
        }
        raw_den = acc14[0];
        raw_std = acc14[1];
#pragma unroll
        for (int c = 0; c < KK; ++c) k0v[c] = acc14[2 + c];
    } else {
        const int oY = GS, oX = GS*GS;
        auto tri = [&](const float* __restrict__ g) -> float {
            float v00 = g[o000]*gz       + g[o000+1]*fz;
            float v01 = g[o000+oY]*gz    + g[o000+oY+1]*fz;
            float v10 = g[o000+oX]*gz    + g[o000+oX+1]*fz;
            float v11 = g[o000+oX+oY]*gz + g[o000+oX+oY+1]*fz;
            return v00*c00 + v01*c01 + v10*c10 + v11*c11;
        };
        raw_den = tri(dgrid);
        raw_std = tri(sgrid);
#pragma unroll
        for (int c = 0; c < KK; ++c) k0v[c] = tri(k0g + c*G3);
    }

    // ---- alpha (deep-negative softplus fast path) + wave scan ----
    float stdv = softplusf(raw_std);
    float alpha[KK], incl[KK];
#pragma unroll
    for (int k = 0; k < KK; ++k) {
        float x  = raw_den + stdv * eps_den[k] + ACT_SHIFT;
        float a  = __expf(x) * 0.5f;
        float al = a - a*a*0.5f;
        alpha[k] = al;
        incl[k]  = 1.f - al + 1e-10f;
    }
#pragma unroll
    for (int d = 1; d < 64; d <<= 1) {
#pragma unroll
        for (int k = 0; k < KK; ++k) {
            float v = __shfl_up(incl[k], d, 64);
            if (lane >= d) incl[k] *= v;
        }
    }
    if (lane == 63) {
#pragma unroll
        for (int k = 0; k < KK; ++k) scanw[wv][k] = incl[k];
    }

    // ---- pack features into 6 held dwords ----
    unsigned f0 = pk2(k0v[0], k0v[1]), f1 = pk2(k0v[2],  k0v[3]);
    unsigned f2 = pk2(k0v[4], k0v[5]), f3 = pk2(k0v[6],  k0v[7]);
    unsigned f4 = pk2(k0v[8], k0v[9]), f5 = pk2(k0v[10], k0v[11]);

    __syncthreads();   // [1] scanw + veb visible

    // ---- wk -> LDS bf16 (freeing registers across the MLP) ----
    {
        float wk[KK];
#pragma unroll
        for (int k = 0; k < KK; ++k) {
            float pref = 1.f;
            for (int pw = 0; pw < wv; ++pw) pref *= scanw[pw][k];
            float ex = __shfl_up(incl[k], 1, 64);
            if (lane == 0) ex = 1.f;
            wk[k] = alpha[k] * (pref * ex);
        }
        unsigned* wp = wkl + s * 6;
#pragma unroll
        for (int i = 0; i < 6; ++i) wp[i] = pk2(wk[2*i], wk[2*i+1]);
    }

    // ---- h1ray[n] = b0[n] + W0[12:39]^T . ve (f32, once per ray) ----
    if (s < 128) {
        float acc = b0[s];
#pragma unroll
        for (int j = 0; j < 27; ++j)
            acc = fmaf(veb[j], w0[(12 + j) * 128 + s], acc);
        h1ray[s] = acc;
    }

    // ================= 2 straight-line MLP chunks ========================
    float p0 = 0.f, p1 = 0.f, p2 = 0.f;
    mlp_chunk<0>(act, h1ray, wkl, b1, b2, eps_rgb, wsb,
                 s, wv, lm, lk, f0, f1, f2, f3, f4, f5, p0, p1, p2);
    mlp_chunk<1>(act, h1ray, wkl, b1, b2, eps_rgb, wsb,
                 s, wv, lm, lk, f0, f1, f2, f3, f4, f5, p0, p1, p2);

    // ================= final block reduction ==============================
#pragma unroll
    for (int d = 32; d > 0; d >>= 1) {
        p0 += __shfl_down(p0, d, 64);
        p1 += __shfl_down(p1, d, 64);
        p2 += __shfl_down(p2, d, 64);
    }
    if (lane == 0) { red[wv][0] = p0; red[wv][1] = p1; red[wv][2] = p2; }
    __syncthreads();
    if (s == 0) {
        float a0 = red[0][0] + red[1][0] + red[2][0] + red[3][0];
        float a1 = red[0][1] + red[1][1] + red[2][1] + red[3][1];
        float a2 = red[0][2] + red[1][2] + red[2][2] + red[3][2];
        out[r*3+0] = 1.f + a0 * (1.f/12.f);
        out[r*3+1] = 1.f + a1 * (1.f/12.f);
        out[r*3+2] = 1.f + a2 * (1.f/12.f);
    }
}

extern "C" void kernel_launch(void* const* d_in, const int* in_sizes, int n_in,
                              void* d_out, int out_size, void* d_ws, size_t ws_size,
                              hipStream_t stream) {
    const float* rays_o  = (const float*)d_in[0];
    const float* rays_d  = (const float*)d_in[1];
    const float* dgrid   = (const float*)d_in[2];
    const float* sgrid   = (const float*)d_in[3];
    const float* k0g     = (const float*)d_in[4];
    const float* w0      = (const float*)d_in[5];
    const float* b0      = (const float*)d_in[6];
    const float* w1      = (const float*)d_in[7];
    const float* b1      = (const float*)d_in[8];
    const float* w2      = (const float*)d_in[9];
    const float* b2      = (const float*)d_in[10];
    const float* eps_den = (const float*)d_in[11];
    const float* eps_rgb = (const float*)d_in[12];
    float* out = (float*)d_out;
    __bf16* wsb = (__bf16*)d_ws;
    char*   gridb = (char*)d_ws + GRID_OFF_B;

    prep_weights<<<88, 256, 0, stream>>>(w0, w1, w2, wsb);
    if (ws_size >= NEED_GRID) {
        prep_grid<<<G3/256, 256, 0, stream>>>(dgrid, sgrid, k0g, (__bf16*)gridb);
        voxgo_fwd<1><<<NRAYS, 256, 0, stream>>>(rays_o, rays_d, dgrid, sgrid, k0g, gridb,
                                                w0, b0, b1, b2, eps_den, eps_rgb, wsb, out);
    } else {
        voxgo_fwd<0><<<NRAYS, 256, 0, stream>>>(rays_o, rays_d, dgrid, sgrid, k0g, gridb,
                                                w0, b0, b1, b2, eps_den, eps_rgb, wsb, out);
    }
}